// Round 3
// baseline (369.569 us; speedup 1.0000x reference)
//
#include <hip/hip_runtime.h>
#include <hip/hip_bf16.h>
#include <math.h>

// S5 SSM layer. B_SZ=16, L=1024, H=256, P=256.
// R13: ONE normal dispatch + tiny memset. Manual co-resident grid barrier
// (512 blocks x 512 thr, LDS 68KB -> exactly 2 blocks/CU x 256 CU = 512 slots).
// Phases: prep -> GEMM1+local-scan (X stays in LDS) -> carry table -> fixup+GEMM2+D*u.
#define BB     16
#define LSEQ   1024
#define HH     256
#define PP     256
#define LC     32
#define NC     (LSEQ/LC)     // 32
#define NCHUNK (BB*NC)       // 512

// workspace byte offsets
#define OFF_W1T  0u          // [512][256] bf16: row 2p=Re(B_bar[p][.]), 2p+1=Im
#define OFF_W2T  262144u     // [256][512] bf16: row h, k=2p -> 2*C_re, 2p+1 -> -2*C_im
#define OFF_PW   524288u     // [33][256] float2: lambda_bar^t
#define OFF_CEND 655360u     // [512][256] float2 chunk-end local states (1 MB)
#define OFF_CARR 1703936u    // [512][256] float2 carry entering each chunk (1 MB)
#define OFF_BAR  2752512u    // grid-barrier counter (zeroed by memsetAsync each launch)

typedef __attribute__((ext_vector_type(8))) short short8;
typedef __attribute__((ext_vector_type(4))) float floatx4;

__device__ __forceinline__ float bf2f(unsigned hs) {
    union { unsigned u; float f; } v; v.u = hs << 16; return v.f;
}
__device__ __forceinline__ unsigned short f2bs(float f) {
    __hip_bfloat16 h = __float2bfloat16(f);
    union { __hip_bfloat16 h; unsigned short s; } v; v.h = h; return v.s;
}
__device__ __forceinline__ unsigned packbf(float r, float i) {
    return (unsigned)f2bs(r) | ((unsigned)f2bs(i) << 16);
}
__device__ __forceinline__ void async16(const void* g, void* l) {
    __builtin_amdgcn_global_load_lds(
        (const __attribute__((address_space(1))) unsigned*)g,
        (__attribute__((address_space(3))) unsigned*)l, 16, 0, 0);
}
__device__ __forceinline__ float2 lam_pow(float lr, float li, float dtt) {
    float m = expf(lr * dtt);
    return make_float2(m * cosf(li * dtt), m * sinf(li * dtt));
}

// Device-wide barrier: monotonic counter, per-block arrival, bounded spin.
// release fence -> buffer_wbl2 sc1 (publish to L3); acquire fence -> buffer_inv sc1.
__device__ __forceinline__ void gridbar(unsigned* cnt, unsigned target) {
    __syncthreads();                                   // drain this block's vmem/lds
    __builtin_amdgcn_fence(__ATOMIC_RELEASE, "agent"); // L2 writeback (cross-XCD publish)
    if (threadIdx.x == 0) {
        __hip_atomic_fetch_add(cnt, 1u, __ATOMIC_RELAXED, __HIP_MEMORY_SCOPE_AGENT);
        for (int it = 0; it < (1 << 20); ++it) {       // bounded: no infinite hang
            if (__hip_atomic_load(cnt, __ATOMIC_RELAXED, __HIP_MEMORY_SCOPE_AGENT) >= target)
                break;
            __builtin_amdgcn_s_sleep(2);
        }
    }
    __syncthreads();
    __builtin_amdgcn_fence(__ATOMIC_ACQUIRE, "agent"); // invalidate stale L1/L2 lines
}

// LDS map (69632 B total, 2 blocks/CU):
//   phase GEMM1 : Asb @0      [2][32][32]bf16  (4 KB)
//                 Bsb @4096   [2][512][32]bf16 (64 KB)
//   phase scan+ : X   @0      [32][520]bf16    (33280 B; stride 520 -> row%128B=16B)
//                 Bsb2@34816  [2][256][32]bf16 (32 KB)
//                 carr@67584  [256]float2      (2 KB)
#define XSTRS 520
#define XSTRD 260
#define BSB2_OFF 34816
#define CARR_OFF 67584

__global__ __launch_bounds__(512, 4) void k_all(
        const float* __restrict__ u, const float* __restrict__ Lr,
        const float* __restrict__ Li, const float* __restrict__ ls,
        const float* __restrict__ Bm, const float* __restrict__ Cm,
        const float* __restrict__ D, float* __restrict__ out,
        char* __restrict__ ws) {
    extern __shared__ char smem[];
    unsigned* bar = (unsigned*)(ws + OFF_BAR);

    const int tid = threadIdx.x, bc = blockIdx.x;
    const int wave = tid >> 6, lane = tid & 63;
    const int q = lane >> 4, rr = lane & 15;
    const int c4 = lane & 3, r4 = lane >> 2;
    const int m0 = bc * LC;

    // ---------------- phase 0: prep (W1T, PW, W2T) ----------------
    if (bc < 256) {
        if (tid < 256) {
            int p = bc, h = tid;
            float lr = Lr[p], li = Li[p];
            float dt = expf(ls[p]);
            float2 lam = lam_pow(lr, li, dt);
            float den = lr * lr + li * li;
            float nr = lam.x - 1.0f, ni = lam.y;
            float cr = (nr * lr + ni * li) / den;    // (lam_bar-1)/Lambda
            float ci = (ni * lr - nr * li) / den;
            float br = Bm[(p * HH + h) * 2 + 0];
            float bi = Bm[(p * HH + h) * 2 + 1];
            unsigned short* w1 = (unsigned short*)(ws + OFF_W1T);
            w1[(2 * p) * 256 + h]     = f2bs(cr * br - ci * bi);
            w1[(2 * p + 1) * 256 + h] = f2bs(cr * bi + ci * br);
            if (tid <= 32)
                ((float2*)(ws + OFF_PW))[tid * 256 + p] = lam_pow(lr, li, dt * (float)tid);
        }
    } else {
        if (tid < 256) {
            int h = bc - 256, p = tid;
            float c_r = Cm[(h * PP + p) * 2 + 0];
            float c_i = Cm[(h * PP + p) * 2 + 1];
            ((unsigned*)(ws + OFF_W2T))[h * 256 + p] = packbf(2.0f * c_r, -2.0f * c_i);
        }
    }
    gridbar(bar, NCHUNK);          // W1T/PW/W2T published

    // ---------------- phase 1: GEMM1 (BM=32, BN=512, K=256) ----------------
    {
        char* Asb = smem;
        char* Bsb = smem + 4096;
        const unsigned short* W1 = (const unsigned short*)(ws + OFF_W1T);
        floatx4 acc[2][4];
        #pragma unroll
        for (int i = 0; i < 2; ++i)
            #pragma unroll
            for (int j = 0; j < 4; ++j) acc[i][j] = (floatx4)0.0f;

        const int arow = tid >> 4, acol4 = (tid & 15) * 4;
        for (int k0 = 0; k0 < 256; k0 += 64) {
            __syncthreads();
            {   // A panel: u 32x64 fp32 -> bf16
                float4 v = *(const float4*)(u + (size_t)(m0 + arow) * 256 + k0 + acol4);
                *(uint2*)(Asb + (acol4 >> 5) * 2048 + arow * 64 + (acol4 & 31) * 2) =
                    make_uint2(packbf(v.x, v.y), packbf(v.z, v.w));
            }
            #pragma unroll
            for (int t = 0; t < 8; ++t) {   // B: 512 rows x 2 panels via DMA
                int idx = t * 8 + wave;     // 0..63
                int pan = idx & 1, rowg = idx >> 1;
                int row = rowg * 16 + r4;
                async16(W1 + (size_t)row * 256 + k0 + pan * 32 + c4 * 8,
                        Bsb + pan * 32768 + row * 64 + c4 * 16);
            }
            __syncthreads();
            #pragma unroll
            for (int ks = 0; ks < 2; ++ks) {
                short8 a0 = *(const short8*)(Asb + ks * 2048 + rr * 64 + q * 16);
                short8 a1 = *(const short8*)(Asb + ks * 2048 + (16 + rr) * 64 + q * 16);
                #pragma unroll
                for (int j = 0; j < 4; ++j) {
                    short8 b = *(const short8*)(Bsb + ks * 32768 +
                                                (wave * 64 + j * 16 + rr) * 64 + q * 16);
                    acc[0][j] = __builtin_amdgcn_mfma_f32_16x16x32_bf16(a0, b, acc[0][j], 0, 0, 0);
                    acc[1][j] = __builtin_amdgcn_mfma_f32_16x16x32_bf16(a1, b, acc[1][j], 0, 0, 0);
                }
            }
        }
        __syncthreads();
        // dump Bu tile (32 x 512) into padded LDS X (overwrites Asb/Bsb head)
        unsigned short* X = (unsigned short*)smem;
        #pragma unroll
        for (int i = 0; i < 2; ++i)
            #pragma unroll
            for (int j = 0; j < 4; ++j)
                #pragma unroll
                for (int r0 = 0; r0 < 4; ++r0)
                    X[(i * 16 + q * 4 + r0) * XSTRS + wave * 64 + j * 16 + rr] =
                        f2bs(acc[i][j][r0]);
        __syncthreads();
    }

    // ---------------- phase 2: local scan (waves 0-3) || W2 prestage (waves 4-7) ----
    if (tid < 256) {
        const int pq = tid;
        const float2 lam = lam_pow(Lr[pq], Li[pq], expf(ls[pq]));
        unsigned* X32 = (unsigned*)smem;
        float xr = 0.0f, xi = 0.0f;
        #pragma unroll
        for (int j = 0; j < LC; ++j) {
            unsigned cv = X32[j * XSTRD + pq];
            float br = bf2f(cv & 0xffffu), bi = bf2f(cv >> 16);
            float nr = fmaf(lam.x, xr, fmaf(-lam.y, xi, br));
            float ni = fmaf(lam.x, xi, fmaf(lam.y, xr, bi));
            xr = nr; xi = ni;
            X32[j * XSTRD + pq] = packbf(xr, xi);   // x_local in place
        }
        ((float2*)(ws + OFF_CEND))[(size_t)bc * 256 + pq] = make_float2(xr, xi);
    } else {
        // prestage W2 panel k0=0 into Bsb2 while the scan runs
        const unsigned short* W2 = (const unsigned short*)(ws + OFF_W2T);
        char* Bsb2 = smem + BSB2_OFF;
        int w4 = wave - 4;
        #pragma unroll
        for (int t = 0; t < 8; ++t) {
            int idx = t * 4 + w4;           // 0..31
            int pan = idx & 1, rowg = idx >> 1;
            int row = rowg * 16 + r4;
            async16(W2 + (size_t)row * 512 + pan * 32 + c4 * 8,
                    Bsb2 + pan * 16384 + row * 64 + c4 * 16);
        }
    }
    gridbar(bar, 2 * NCHUNK);      // CEND published

    // ---------------- phase 3: carry chains (blocks 0..15, one batch each) --------
    if (bc < BB && tid < 256) {
        const int b = bc, p = tid;
        const float2* cend = (const float2*)(ws + OFF_CEND);
        float2* carr = (float2*)(ws + OFF_CARR);
        const float2 g = lam_pow(Lr[p], Li[p], expf(ls[p]) * (float)LC);
        float sr = 0.0f, si = 0.0f;
        #pragma unroll
        for (int c = 0; c < NC; ++c) {
            size_t idx = (size_t)(b * NC + c) * 256 + p;
            carr[idx] = make_float2(sr, si);
            float2 e = cend[idx];
            float nr = fmaf(g.x, sr, fmaf(-g.y, si, e.x));
            float ni = fmaf(g.x, si, fmaf(g.y, sr, e.y));
            sr = nr; si = ni;
        }
    }
    gridbar(bar, 3 * NCHUNK);      // CARR published

    // ---------------- phase 4: carry load + fixup X in place ----------------------
    {
        float2* carrs = (float2*)(smem + CARR_OFF);
        if (tid < 256)
            carrs[tid] = ((const float2*)(ws + OFF_CARR))[(size_t)bc * 256 + tid];
        __syncthreads();
        unsigned* X32 = (unsigned*)smem;
        const float2* pw = (const float2*)(ws + OFF_PW);
        const int frow = tid >> 4, fcol = tid & 15;
        const float2* pwr = pw + (size_t)(frow + 1) * 256;
        #pragma unroll 4
        for (int e = 0; e < 16; ++e) {
            int p = fcol + e * 16;
            unsigned cv = X32[frow * XSTRD + p];
            float2 pwv = pwr[p];
            float2 cav = carrs[p];
            float fr = pwv.x * cav.x - pwv.y * cav.y;
            float fi = pwv.x * cav.y + pwv.y * cav.x;
            X32[frow * XSTRD + p] =
                packbf(bf2f(cv & 0xffffu) + fr, bf2f(cv >> 16) + fi);
        }
    }

    // ---------------- phase 5: GEMM2 (BM=32, BN=256, K=512) + D*u -----------------
    {
        const unsigned short* W2 = (const unsigned short*)(ws + OFF_W2T);
        char* Bsb2 = smem + BSB2_OFF;
        const char* Xb = (const char*)smem;
        floatx4 acc[2][2];
        #pragma unroll
        for (int i = 0; i < 2; ++i)
            #pragma unroll
            for (int j = 0; j < 2; ++j) acc[i][j] = (floatx4)0.0f;

        for (int k0 = 0; k0 < 512; k0 += 64) {
            if (k0) {
                __syncthreads();   // previous MFMA done; safe to overwrite Bsb2
                #pragma unroll
                for (int t = 0; t < 4; ++t) {
                    int idx = t * 8 + wave;        // 0..31
                    int pan = idx & 1, rowg = idx >> 1;
                    int row = rowg * 16 + r4;
                    async16(W2 + (size_t)row * 512 + k0 + pan * 32 + c4 * 8,
                            Bsb2 + pan * 16384 + row * 64 + c4 * 16);
                }
            }
            __syncthreads();       // staged panels visible (also fixup->MFMA at k0=0)
            #pragma unroll
            for (int ks = 0; ks < 2; ++ks) {
                short8 a[2], bfr[2];
                #pragma unroll
                for (int i = 0; i < 2; ++i)
                    a[i] = *(const short8*)(Xb + (i * 16 + rr) * (XSTRS * 2) +
                                            k0 * 2 + ks * 64 + q * 16);
                #pragma unroll
                for (int j = 0; j < 2; ++j)
                    bfr[j] = *(const short8*)(Bsb2 + ks * 16384 +
                                              (wave * 32 + j * 16 + rr) * 64 + q * 16);
                #pragma unroll
                for (int i = 0; i < 2; ++i)
                    #pragma unroll
                    for (int j = 0; j < 2; ++j)
                        acc[i][j] = __builtin_amdgcn_mfma_f32_16x16x32_bf16(a[i], bfr[j], acc[i][j], 0, 0, 0);
            }
        }

        #pragma unroll
        for (int i = 0; i < 2; ++i) {
            int mbase = m0 + i * 16 + q * 4;
            #pragma unroll
            for (int j = 0; j < 2; ++j) {
                int col = wave * 32 + j * 16 + rr;
                #pragma unroll
                for (int r0 = 0; r0 < 4; ++r0) {
                    int rw = mbase + r0;
                    size_t gi = (size_t)rw * 256 + col;
                    out[gi] = acc[i][j][r0] + D[col] * u[gi];
                }
            }
        }
    }
}

extern "C" void kernel_launch(void* const* d_in, const int* in_sizes, int n_in,
                              void* d_out, int out_size, void* d_ws, size_t ws_size,
                              hipStream_t stream) {
    const float* u  = (const float*)d_in[0];
    const float* Lr = (const float*)d_in[1];
    const float* Li = (const float*)d_in[2];
    const float* Bm = (const float*)d_in[3];
    const float* Cm = (const float*)d_in[4];
    const float* D  = (const float*)d_in[5];
    const float* ls = (const float*)d_in[6];
    float* out = (float*)d_out;
    char* ws = (char*)d_ws;

    // zero the grid-barrier counter (workspace is re-poisoned before every launch)
    hipMemsetAsync(ws + OFF_BAR, 0, 64, stream);
    k_all<<<NCHUNK, 512, 69632, stream>>>(u, Lr, Li, ls, Bm, Cm, D, out, ws);
}

// Round 4
// 152.143 us; speedup vs baseline: 2.4291x; 2.4291x over previous
//
#include <hip/hip_runtime.h>
#include <hip/hip_bf16.h>
#include <math.h>

// S5 SSM layer. B_SZ=16, L=1024, H=256, P=256.
// R14: ONE dispatch, FENCELESS grid barriers. All cross-block writes use
// agent-scope (sc1) stores -> coherent at L3; consumers' first touch is a clean
// L2 miss, so no buffer_wbl2/buffer_inv needed (R13's 3x~100us fence cost).
// Phases: prep -> GEMM1+local-scan (X stays in LDS) -> carry table -> fixup+GEMM2+D*u.
#define BB     16
#define LSEQ   1024
#define HH     256
#define PP     256
#define LC     32
#define NC     (LSEQ/LC)     // 32
#define NCHUNK (BB*NC)       // 512

// workspace byte offsets
#define OFF_W1T  0u          // [512][256] bf16: row 2p=Re(B_bar[p][.]), 2p+1=Im
#define OFF_W2T  262144u     // [256][512] bf16: row h, k=2p -> 2*C_re, 2p+1 -> -2*C_im
#define OFF_PW   524288u     // [33][256] float2: lambda_bar^t
#define OFF_CEND 655360u     // [512][256] float2 chunk-end local states (1 MB)
#define OFF_CARR 1703936u    // [512][256] float2 carry entering each chunk (1 MB)
#define OFF_BAR  2752512u    // grid-barrier counter (zeroed by memsetAsync each launch)

typedef __attribute__((ext_vector_type(8))) short short8;
typedef __attribute__((ext_vector_type(4))) float floatx4;
typedef unsigned long long ull;

__device__ __forceinline__ float bf2f(unsigned hs) {
    union { unsigned u; float f; } v; v.u = hs << 16; return v.f;
}
__device__ __forceinline__ unsigned short f2bs(float f) {
    __hip_bfloat16 h = __float2bfloat16(f);
    union { __hip_bfloat16 h; unsigned short s; } v; v.h = h; return v.s;
}
__device__ __forceinline__ unsigned packbf(float r, float i) {
    return (unsigned)f2bs(r) | ((unsigned)f2bs(i) << 16);
}
__device__ __forceinline__ void async16(const void* g, void* l) {
    __builtin_amdgcn_global_load_lds(
        (const __attribute__((address_space(1))) unsigned*)g,
        (__attribute__((address_space(3))) unsigned*)l, 16, 0, 0);
}
__device__ __forceinline__ float2 lam_pow(float lr, float li, float dtt) {
    float m = expf(lr * dtt);
    return make_float2(m * cosf(li * dtt), m * sinf(li * dtt));
}
__device__ __forceinline__ void cohst32(unsigned* p, unsigned v) {
    __hip_atomic_store(p, v, __ATOMIC_RELAXED, __HIP_MEMORY_SCOPE_AGENT);
}
__device__ __forceinline__ void cohst64(ull* p, float2 v) {
    ull b; __builtin_memcpy(&b, &v, 8);
    __hip_atomic_store(p, b, __ATOMIC_RELAXED, __HIP_MEMORY_SCOPE_AGENT);
}

// Device-wide barrier, NO cache fences. Prior sc1 stores are already coherent;
// explicit vmcnt drain guarantees they completed before this block's arrival.
__device__ __forceinline__ void gridbar(unsigned* cnt, unsigned target) {
    asm volatile("s_waitcnt vmcnt(0)" ::: "memory");
    __syncthreads();
    if (threadIdx.x == 0) {
        __hip_atomic_fetch_add(cnt, 1u, __ATOMIC_RELAXED, __HIP_MEMORY_SCOPE_AGENT);
        for (int it = 0; it < (1 << 20); ++it) {       // bounded: no infinite hang
            if (__hip_atomic_load(cnt, __ATOMIC_RELAXED, __HIP_MEMORY_SCOPE_AGENT) >= target)
                break;
            __builtin_amdgcn_s_sleep(2);
        }
    }
    __syncthreads();
}

// LDS map (69632 B total, 2 blocks/CU):
//   phase GEMM1 : Asb @0      [2][32][32]bf16  (4 KB)
//                 Bsb @4096   [2][512][32]bf16 (64 KB)
//   phase scan+ : X   @0      [32][520]bf16    (33280 B; stride 520 -> row%128B=16B)
//                 Bsb2@34816  [2][256][32]bf16 (32 KB)
//                 carr@67584  [256]float2      (2 KB)
#define XSTRS 520
#define XSTRD 260
#define BSB2_OFF 34816
#define CARR_OFF 67584

__global__ __launch_bounds__(512, 4) void k_all(
        const float* __restrict__ u, const float* __restrict__ Lr,
        const float* __restrict__ Li, const float* __restrict__ ls,
        const float* __restrict__ Bm, const float* __restrict__ Cm,
        const float* __restrict__ D, float* __restrict__ out,
        char* __restrict__ ws) {
    extern __shared__ char smem[];
    unsigned* bar = (unsigned*)(ws + OFF_BAR);

    const int tid = threadIdx.x, bc = blockIdx.x;
    const int wave = tid >> 6, lane = tid & 63;
    const int q = lane >> 4, rr = lane & 15;
    const int c4 = lane & 3, r4 = lane >> 2;
    const int m0 = bc * LC;

    // ---------------- phase 0: prep (W1T, PW, W2T) via coherent stores ----------
    if (bc < 256) {
        if (tid < 128) {
            int p = bc, t = tid;
            float lr = Lr[p], li = Li[p];
            float dt = expf(ls[p]);
            float2 lam = lam_pow(lr, li, dt);
            float den = lr * lr + li * li;
            float nr = lam.x - 1.0f, ni = lam.y;
            float cr = (nr * lr + ni * li) / den;    // (lam_bar-1)/Lambda
            float ci = (ni * lr - nr * li) / den;
            // B[p][2t][re,im], B[p][2t+1][re,im] as one float4
            float4 bv = *(const float4*)(Bm + (size_t)p * 512 + 4 * t);
            unsigned rev = packbf(cr * bv.x - ci * bv.y, cr * bv.z - ci * bv.w);
            unsigned imv = packbf(cr * bv.y + ci * bv.x, cr * bv.w + ci * bv.z);
            unsigned* w1u = (unsigned*)(ws + OFF_W1T);
            cohst32(&w1u[(2 * p) * 128 + t], rev);
            cohst32(&w1u[(2 * p + 1) * 128 + t], imv);
            if (t <= 32)
                cohst64((ull*)(ws + OFF_PW) + (size_t)t * 256 + p,
                        lam_pow(lr, li, dt * (float)t));
        }
    } else {
        if (tid < 256) {
            int h = bc - 256, p = tid;
            float c_r = Cm[(h * PP + p) * 2 + 0];
            float c_i = Cm[(h * PP + p) * 2 + 1];
            cohst32((unsigned*)(ws + OFF_W2T) + h * 256 + p, packbf(2.0f * c_r, -2.0f * c_i));
        }
    }
    gridbar(bar, NCHUNK);          // W1T/PW/W2T at coherent point

    // ---------------- phase 1: GEMM1 (BM=32, BN=512, K=256) ----------------
    {
        char* Asb = smem;
        char* Bsb = smem + 4096;
        const unsigned short* W1 = (const unsigned short*)(ws + OFF_W1T);
        floatx4 acc[2][4];
        #pragma unroll
        for (int i = 0; i < 2; ++i)
            #pragma unroll
            for (int j = 0; j < 4; ++j) acc[i][j] = (floatx4)0.0f;

        const int arow = tid >> 4, acol4 = (tid & 15) * 4;
        for (int k0 = 0; k0 < 256; k0 += 64) {
            __syncthreads();
            {   // A panel: u 32x64 fp32 -> bf16
                float4 v = *(const float4*)(u + (size_t)(m0 + arow) * 256 + k0 + acol4);
                *(uint2*)(Asb + (acol4 >> 5) * 2048 + arow * 64 + (acol4 & 31) * 2) =
                    make_uint2(packbf(v.x, v.y), packbf(v.z, v.w));
            }
            #pragma unroll
            for (int t = 0; t < 8; ++t) {   // B: 512 rows x 2 panels via DMA
                int idx = t * 8 + wave;     // 0..63
                int pan = idx & 1, rowg = idx >> 1;
                int row = rowg * 16 + r4;
                async16(W1 + (size_t)row * 256 + k0 + pan * 32 + c4 * 8,
                        Bsb + pan * 32768 + row * 64 + c4 * 16);
            }
            __syncthreads();
            #pragma unroll
            for (int ks = 0; ks < 2; ++ks) {
                short8 a0 = *(const short8*)(Asb + ks * 2048 + rr * 64 + q * 16);
                short8 a1 = *(const short8*)(Asb + ks * 2048 + (16 + rr) * 64 + q * 16);
                #pragma unroll
                for (int j = 0; j < 4; ++j) {
                    short8 b = *(const short8*)(Bsb + ks * 32768 +
                                                (wave * 64 + j * 16 + rr) * 64 + q * 16);
                    acc[0][j] = __builtin_amdgcn_mfma_f32_16x16x32_bf16(a0, b, acc[0][j], 0, 0, 0);
                    acc[1][j] = __builtin_amdgcn_mfma_f32_16x16x32_bf16(a1, b, acc[1][j], 0, 0, 0);
                }
            }
        }
        __syncthreads();
        // dump Bu tile (32 x 512) into padded LDS X (overwrites Asb/Bsb head)
        unsigned short* X = (unsigned short*)smem;
        #pragma unroll
        for (int i = 0; i < 2; ++i)
            #pragma unroll
            for (int j = 0; j < 4; ++j)
                #pragma unroll
                for (int r0 = 0; r0 < 4; ++r0)
                    X[(i * 16 + q * 4 + r0) * XSTRS + wave * 64 + j * 16 + rr] =
                        f2bs(acc[i][j][r0]);
        __syncthreads();
    }

    // ---------------- phase 2: local scan (waves 0-3) || W2 prestage (waves 4-7) ----
    if (tid < 256) {
        const int pq = tid;
        const float2 lam = lam_pow(Lr[pq], Li[pq], expf(ls[pq]));
        unsigned* X32 = (unsigned*)smem;
        float xr = 0.0f, xi = 0.0f;
        #pragma unroll
        for (int j = 0; j < LC; ++j) {
            unsigned cv = X32[j * XSTRD + pq];
            float br = bf2f(cv & 0xffffu), bi = bf2f(cv >> 16);
            float nr = fmaf(lam.x, xr, fmaf(-lam.y, xi, br));
            float ni = fmaf(lam.x, xi, fmaf(lam.y, xr, bi));
            xr = nr; xi = ni;
            X32[j * XSTRD + pq] = packbf(xr, xi);   // x_local in place
        }
        cohst64((ull*)(ws + OFF_CEND) + (size_t)bc * 256 + pq, make_float2(xr, xi));
    } else {
        // prestage W2 panel k0=0 into Bsb2 while the scan runs
        const unsigned short* W2 = (const unsigned short*)(ws + OFF_W2T);
        char* Bsb2 = smem + BSB2_OFF;
        int w4 = wave - 4;
        #pragma unroll
        for (int t = 0; t < 8; ++t) {
            int idx = t * 4 + w4;           // 0..31
            int pan = idx & 1, rowg = idx >> 1;
            int row = rowg * 16 + r4;
            async16(W2 + (size_t)row * 512 + pan * 32 + c4 * 8,
                    Bsb2 + pan * 16384 + row * 64 + c4 * 16);
        }
    }
    gridbar(bar, 2 * NCHUNK);      // CEND at coherent point

    // ---------------- phase 3: carry chains (blocks 0..15, one batch each) --------
    if (bc < BB && tid < 256) {
        const int b = bc, p = tid;
        const float2* cend = (const float2*)(ws + OFF_CEND);
        const float2 g = lam_pow(Lr[p], Li[p], expf(ls[p]) * (float)LC);
        float sr = 0.0f, si = 0.0f;
        #pragma unroll
        for (int c = 0; c < NC; ++c) {
            size_t idx = (size_t)(b * NC + c) * 256 + p;
            cohst64((ull*)(ws + OFF_CARR) + idx, make_float2(sr, si));
            float2 e = cend[idx];
            float nr = fmaf(g.x, sr, fmaf(-g.y, si, e.x));
            float ni = fmaf(g.x, si, fmaf(g.y, sr, e.y));
            sr = nr; si = ni;
        }
    }
    gridbar(bar, 3 * NCHUNK);      // CARR at coherent point

    // ---------------- phase 4: carry load + fixup X in place ----------------------
    {
        float2* carrs = (float2*)(smem + CARR_OFF);
        if (tid < 256)
            carrs[tid] = ((const float2*)(ws + OFF_CARR))[(size_t)bc * 256 + tid];
        __syncthreads();
        unsigned* X32 = (unsigned*)smem;
        const float2* pw = (const float2*)(ws + OFF_PW);
        const int frow = tid >> 4, fcol = tid & 15;
        const float2* pwr = pw + (size_t)(frow + 1) * 256;
        #pragma unroll 4
        for (int e = 0; e < 16; ++e) {
            int p = fcol + e * 16;
            unsigned cv = X32[frow * XSTRD + p];
            float2 pwv = pwr[p];
            float2 cav = carrs[p];
            float fr = pwv.x * cav.x - pwv.y * cav.y;
            float fi = pwv.x * cav.y + pwv.y * cav.x;
            X32[frow * XSTRD + p] =
                packbf(bf2f(cv & 0xffffu) + fr, bf2f(cv >> 16) + fi);
        }
    }

    // ---------------- phase 5: GEMM2 (BM=32, BN=256, K=512) + D*u -----------------
    {
        const unsigned short* W2 = (const unsigned short*)(ws + OFF_W2T);
        char* Bsb2 = smem + BSB2_OFF;
        const char* Xb = (const char*)smem;
        floatx4 acc[2][2];
        #pragma unroll
        for (int i = 0; i < 2; ++i)
            #pragma unroll
            for (int j = 0; j < 2; ++j) acc[i][j] = (floatx4)0.0f;

        for (int k0 = 0; k0 < 512; k0 += 64) {
            if (k0) {
                __syncthreads();   // previous MFMA done; safe to overwrite Bsb2
                #pragma unroll
                for (int t = 0; t < 4; ++t) {
                    int idx = t * 8 + wave;        // 0..31
                    int pan = idx & 1, rowg = idx >> 1;
                    int row = rowg * 16 + r4;
                    async16(W2 + (size_t)row * 512 + k0 + pan * 32 + c4 * 8,
                            Bsb2 + pan * 16384 + row * 64 + c4 * 16);
                }
            }
            __syncthreads();       // staged panels visible (also fixup->MFMA at k0=0)
            #pragma unroll
            for (int ks = 0; ks < 2; ++ks) {
                short8 a[2], bfr[2];
                #pragma unroll
                for (int i = 0; i < 2; ++i)
                    a[i] = *(const short8*)(Xb + (i * 16 + rr) * (XSTRS * 2) +
                                            k0 * 2 + ks * 64 + q * 16);
                #pragma unroll
                for (int j = 0; j < 2; ++j)
                    bfr[j] = *(const short8*)(Bsb2 + ks * 16384 +
                                              (wave * 32 + j * 16 + rr) * 64 + q * 16);
                #pragma unroll
                for (int i = 0; i < 2; ++i)
                    #pragma unroll
                    for (int j = 0; j < 2; ++j)
                        acc[i][j] = __builtin_amdgcn_mfma_f32_16x16x32_bf16(a[i], bfr[j], acc[i][j], 0, 0, 0);
            }
        }

        #pragma unroll
        for (int i = 0; i < 2; ++i) {
            int mbase = m0 + i * 16 + q * 4;
            #pragma unroll
            for (int j = 0; j < 2; ++j) {
                int col = wave * 32 + j * 16 + rr;
                #pragma unroll
                for (int r0 = 0; r0 < 4; ++r0) {
                    int rw = mbase + r0;
                    size_t gi = (size_t)rw * 256 + col;
                    out[gi] = acc[i][j][r0] + D[col] * u[gi];
                }
            }
        }
    }
}

extern "C" void kernel_launch(void* const* d_in, const int* in_sizes, int n_in,
                              void* d_out, int out_size, void* d_ws, size_t ws_size,
                              hipStream_t stream) {
    const float* u  = (const float*)d_in[0];
    const float* Lr = (const float*)d_in[1];
    const float* Li = (const float*)d_in[2];
    const float* Bm = (const float*)d_in[3];
    const float* Cm = (const float*)d_in[4];
    const float* D  = (const float*)d_in[5];
    const float* ls = (const float*)d_in[6];
    float* out = (float*)d_out;
    char* ws = (char*)d_ws;

    // zero the grid-barrier counter (workspace is re-poisoned before every launch)
    hipMemsetAsync(ws + OFF_BAR, 0, 64, stream);
    k_all<<<NCHUNK, 512, 69632, stream>>>(u, Lr, Li, ls, Bm, Cm, D, out, ws);
}

// Round 5
// 109.941 us; speedup vs baseline: 3.3615x; 1.3839x over previous
//
#include <hip/hip_runtime.h>
#include <hip/hip_bf16.h>
#include <math.h>

// S5 SSM layer. B_SZ=16, L=1024, H=256, P=256.
// R15: ONE dispatch, TWO fenceless TREE barriers (16->32->root, sense flags).
// Carry phase eliminated: each block computes its own carry via a fixed-31-iter
// predicated prefix over CEND (loads independent -> pipelined; masked terms = 0).
// Phases: prep -> [bar0] -> GEMM1 -> scan||W2-prestage -> [bar1] -> prefix ->
//         fixup -> GEMM2 + D*u.
#define BB     16
#define LSEQ   1024
#define HH     256
#define PP     256
#define LC     32
#define NC     (LSEQ/LC)     // 32
#define NCHUNK (BB*NC)       // 512

// workspace byte offsets
#define OFF_W1T  0u          // [512][256] bf16: row 2p=Re(B_bar[p][.]), 2p+1=Im
#define OFF_W2T  262144u     // [256][512] bf16: row h, k=2p -> 2*C_re, 2p+1 -> -2*C_im
#define OFF_PW   524288u     // [33][256] float2: lambda_bar^t
#define OFF_CEND 655360u     // [512][256] float2 chunk-end local states (1 MB)
#define OFF_BAR  2752512u    // tree-barrier area: 2 instances x 8192 B (memset each launch)

typedef __attribute__((ext_vector_type(8))) short short8;
typedef __attribute__((ext_vector_type(4))) float floatx4;
typedef unsigned long long ull;

__device__ __forceinline__ float bf2f(unsigned hs) {
    union { unsigned u; float f; } v; v.u = hs << 16; return v.f;
}
__device__ __forceinline__ unsigned short f2bs(float f) {
    __hip_bfloat16 h = __float2bfloat16(f);
    union { __hip_bfloat16 h; unsigned short s; } v; v.h = h; return v.s;
}
__device__ __forceinline__ unsigned packbf(float r, float i) {
    return (unsigned)f2bs(r) | ((unsigned)f2bs(i) << 16);
}
__device__ __forceinline__ void async16(const void* g, void* l) {
    __builtin_amdgcn_global_load_lds(
        (const __attribute__((address_space(1))) unsigned*)g,
        (__attribute__((address_space(3))) unsigned*)l, 16, 0, 0);
}
__device__ __forceinline__ float2 lam_pow(float lr, float li, float dtt) {
    float m = expf(lr * dtt);
    return make_float2(m * cosf(li * dtt), m * sinf(li * dtt));
}
__device__ __forceinline__ void cohst32(unsigned* p, unsigned v) {
    __hip_atomic_store(p, v, __ATOMIC_RELAXED, __HIP_MEMORY_SCOPE_AGENT);
}
__device__ __forceinline__ void cohst64(ull* p, float2 v) {
    ull b; __builtin_memcpy(&b, &v, 8);
    __hip_atomic_store(p, b, __ATOMIC_RELAXED, __HIP_MEMORY_SCOPE_AGENT);
}

// Two-level grid barrier, no cache fences (all cross-block data uses sc1 stores).
// Groups of 16 blocks -> per-group counter (own cacheline); 32 group leaders ->
// root counter; release root_flag -> group_flags. Max same-line pollers: 31.
__device__ __forceinline__ void treebar(char* base, int inst) {
    asm volatile("s_waitcnt vmcnt(0)" ::: "memory");   // prior sc1 stores done
    __syncthreads();
    if (threadIdx.x == 0) {
        char* b = base + inst * 8192;
        const unsigned g = blockIdx.x >> 4;            // 32 groups of 16
        unsigned* gcnt  = (unsigned*)(b + g * 64);
        unsigned* gflag = (unsigned*)(b + 2048 + g * 64);
        unsigned* rcnt  = (unsigned*)(b + 4096);
        unsigned* rflag = (unsigned*)(b + 4160);
        unsigned r = __hip_atomic_fetch_add(gcnt, 1u, __ATOMIC_RELAXED,
                                            __HIP_MEMORY_SCOPE_AGENT);
        if (r == 15) {                                 // last arriver = leader
            unsigned rr = __hip_atomic_fetch_add(rcnt, 1u, __ATOMIC_RELAXED,
                                                 __HIP_MEMORY_SCOPE_AGENT);
            if (rr == 31) {
                __hip_atomic_store(rflag, 1u, __ATOMIC_RELAXED, __HIP_MEMORY_SCOPE_AGENT);
            } else {
                for (int it = 0; it < (1 << 18); ++it) {   // bounded: no hang
                    if (__hip_atomic_load(rflag, __ATOMIC_RELAXED, __HIP_MEMORY_SCOPE_AGENT))
                        break;
                    __builtin_amdgcn_s_sleep(4);
                }
            }
            __hip_atomic_store(gflag, 1u, __ATOMIC_RELAXED, __HIP_MEMORY_SCOPE_AGENT);
        } else {
            for (int it = 0; it < (1 << 18); ++it) {
                if (__hip_atomic_load(gflag, __ATOMIC_RELAXED, __HIP_MEMORY_SCOPE_AGENT))
                    break;
                __builtin_amdgcn_s_sleep(4);
            }
        }
    }
    __syncthreads();
}

// LDS map (69632 B total, 2 blocks/CU):
//   phase GEMM1 : Asb @0      [2][32][32]bf16  (4 KB)
//                 Bsb @4096   [2][512][32]bf16 (64 KB)
//   phase scan+ : X   @0      [32][520]bf16    (33280 B; stride 520 -> row%128B=16B)
//                 Bsb2@34816  [2][256][32]bf16 (32 KB)
//                 carr@67584  [256]float2      (2 KB)
#define XSTRS 520
#define XSTRD 260
#define BSB2_OFF 34816
#define CARR_OFF 67584

__global__ __launch_bounds__(512, 4) void k_all(
        const float* __restrict__ u, const float* __restrict__ Lr,
        const float* __restrict__ Li, const float* __restrict__ ls,
        const float* __restrict__ Bm, const float* __restrict__ Cm,
        const float* __restrict__ D, float* __restrict__ out,
        char* __restrict__ ws) {
    extern __shared__ char smem[];
    char* barbase = ws + OFF_BAR;

    const int tid = threadIdx.x, bc = blockIdx.x;
    const int wave = tid >> 6, lane = tid & 63;
    const int q = lane >> 4, rr = lane & 15;
    const int c4 = lane & 3, r4 = lane >> 2;
    const int m0 = bc * LC;

    // ---------------- phase 0: prep (W1T, PW, W2T) via coherent stores ----------
    if (bc < 256) {
        if (tid < 128) {
            int p = bc, t = tid;
            float lr = Lr[p], li = Li[p];
            float dt = expf(ls[p]);
            float2 lam = lam_pow(lr, li, dt);
            float den = lr * lr + li * li;
            float nr = lam.x - 1.0f, ni = lam.y;
            float cr = (nr * lr + ni * li) / den;    // (lam_bar-1)/Lambda
            float ci = (ni * lr - nr * li) / den;
            // B[p][2t][re,im], B[p][2t+1][re,im] as one float4
            float4 bv = *(const float4*)(Bm + (size_t)p * 512 + 4 * t);
            unsigned rev = packbf(cr * bv.x - ci * bv.y, cr * bv.z - ci * bv.w);
            unsigned imv = packbf(cr * bv.y + ci * bv.x, cr * bv.w + ci * bv.z);
            unsigned* w1u = (unsigned*)(ws + OFF_W1T);
            cohst32(&w1u[(2 * p) * 128 + t], rev);
            cohst32(&w1u[(2 * p + 1) * 128 + t], imv);
            if (t <= 32)
                cohst64((ull*)(ws + OFF_PW) + (size_t)t * 256 + p,
                        lam_pow(lr, li, dt * (float)t));
        }
    } else {
        if (tid < 256) {
            int h = bc - 256, p = tid;
            float c_r = Cm[(h * PP + p) * 2 + 0];
            float c_i = Cm[(h * PP + p) * 2 + 1];
            cohst32((unsigned*)(ws + OFF_W2T) + h * 256 + p, packbf(2.0f * c_r, -2.0f * c_i));
        }
    }
    treebar(barbase, 0);           // W1T/PW/W2T at coherent point

    // ---------------- phase 1: GEMM1 (BM=32, BN=512, K=256) ----------------
    {
        char* Asb = smem;
        char* Bsb = smem + 4096;
        const unsigned short* W1 = (const unsigned short*)(ws + OFF_W1T);
        floatx4 acc[2][4];
        #pragma unroll
        for (int i = 0; i < 2; ++i)
            #pragma unroll
            for (int j = 0; j < 4; ++j) acc[i][j] = (floatx4)0.0f;

        const int arow = tid >> 4, acol4 = (tid & 15) * 4;
        for (int k0 = 0; k0 < 256; k0 += 64) {
            __syncthreads();
            {   // A panel: u 32x64 fp32 -> bf16
                float4 v = *(const float4*)(u + (size_t)(m0 + arow) * 256 + k0 + acol4);
                *(uint2*)(Asb + (acol4 >> 5) * 2048 + arow * 64 + (acol4 & 31) * 2) =
                    make_uint2(packbf(v.x, v.y), packbf(v.z, v.w));
            }
            #pragma unroll
            for (int t = 0; t < 8; ++t) {   // B: 512 rows x 2 panels via DMA
                int idx = t * 8 + wave;     // 0..63
                int pan = idx & 1, rowg = idx >> 1;
                int row = rowg * 16 + r4;
                async16(W1 + (size_t)row * 256 + k0 + pan * 32 + c4 * 8,
                        Bsb + pan * 32768 + row * 64 + c4 * 16);
            }
            __syncthreads();
            #pragma unroll
            for (int ks = 0; ks < 2; ++ks) {
                short8 a0 = *(const short8*)(Asb + ks * 2048 + rr * 64 + q * 16);
                short8 a1 = *(const short8*)(Asb + ks * 2048 + (16 + rr) * 64 + q * 16);
                #pragma unroll
                for (int j = 0; j < 4; ++j) {
                    short8 b = *(const short8*)(Bsb + ks * 32768 +
                                                (wave * 64 + j * 16 + rr) * 64 + q * 16);
                    acc[0][j] = __builtin_amdgcn_mfma_f32_16x16x32_bf16(a0, b, acc[0][j], 0, 0, 0);
                    acc[1][j] = __builtin_amdgcn_mfma_f32_16x16x32_bf16(a1, b, acc[1][j], 0, 0, 0);
                }
            }
        }
        __syncthreads();
        // dump Bu tile (32 x 512) into padded LDS X (overwrites Asb/Bsb head)
        unsigned short* X = (unsigned short*)smem;
        #pragma unroll
        for (int i = 0; i < 2; ++i)
            #pragma unroll
            for (int j = 0; j < 4; ++j)
                #pragma unroll
                for (int r0 = 0; r0 < 4; ++r0)
                    X[(i * 16 + q * 4 + r0) * XSTRS + wave * 64 + j * 16 + rr] =
                        f2bs(acc[i][j][r0]);
        __syncthreads();
    }

    // ---------------- phase 2: local scan (waves 0-3) || W2 prestage (waves 4-7) ----
    if (tid < 256) {
        const int pq = tid;
        const float2 lam = lam_pow(Lr[pq], Li[pq], expf(ls[pq]));
        unsigned* X32 = (unsigned*)smem;
        float xr = 0.0f, xi = 0.0f;
        #pragma unroll
        for (int j = 0; j < LC; ++j) {
            unsigned cv = X32[j * XSTRD + pq];
            float br = bf2f(cv & 0xffffu), bi = bf2f(cv >> 16);
            float nr = fmaf(lam.x, xr, fmaf(-lam.y, xi, br));
            float ni = fmaf(lam.x, xi, fmaf(lam.y, xr, bi));
            xr = nr; xi = ni;
            X32[j * XSTRD + pq] = packbf(xr, xi);   // x_local in place
        }
        cohst64((ull*)(ws + OFF_CEND) + (size_t)bc * 256 + pq, make_float2(xr, xi));
    } else {
        // prestage W2 panel k0=0 into Bsb2 while the scan runs
        const unsigned short* W2 = (const unsigned short*)(ws + OFF_W2T);
        char* Bsb2 = smem + BSB2_OFF;
        int w4 = wave - 4;
        #pragma unroll
        for (int t = 0; t < 8; ++t) {
            int idx = t * 4 + w4;           // 0..31
            int pan = idx & 1, rowg = idx >> 1;
            int row = rowg * 16 + r4;
            async16(W2 + (size_t)row * 512 + pan * 32 + c4 * 8,
                    Bsb2 + pan * 16384 + row * 64 + c4 * 16);
        }
    }
    treebar(barbase, 1);           // CEND at coherent point

    // ---------------- phase 3: per-block carry via fixed-31 predicated prefix ----
    // carry_c = sum_{k=0}^{c-1} g^k * e_{c-1-k};  masked terms contribute exact 0.
    {
        float2* carrs = (float2*)(smem + CARR_OFF);
        if (tid < 256) {
            const int p = tid;
            const int c = bc & (NC - 1);         // chunk index within batch
            const int b0 = bc & ~(NC - 1);       // first chunk of this batch
            const float2* cend = (const float2*)(ws + OFF_CEND);
            const float2 g = lam_pow(Lr[p], Li[p], expf(ls[p]) * (float)LC);
            float sr = 0.0f, si = 0.0f;
            float gpr = 1.0f, gpi = 0.0f;        // g^k
            #pragma unroll
            for (int k = 0; k < NC - 1; ++k) {   // fixed trip count -> pipelined loads
                int idx = c - 1 - k; idx = idx < 0 ? 0 : idx;
                float2 e = cend[(size_t)(b0 + idx) * 256 + p];
                float er = (k < c) ? e.x : 0.0f;
                float ei = (k < c) ? e.y : 0.0f;
                sr = fmaf(gpr, er, fmaf(-gpi, ei, sr));
                si = fmaf(gpr, ei, fmaf(gpi, er, si));
                float t2 = gpr * g.x - gpi * g.y;
                gpi = gpr * g.y + gpi * g.x; gpr = t2;
            }
            carrs[p] = make_float2(sr, si);
        }
        __syncthreads();
    }

    // ---------------- phase 4: fixup X in place ----------------------------------
    {
        float2* carrs = (float2*)(smem + CARR_OFF);
        unsigned* X32 = (unsigned*)smem;
        const float2* pw = (const float2*)(ws + OFF_PW);
        const int frow = tid >> 4, fcol = tid & 15;
        const float2* pwr = pw + (size_t)(frow + 1) * 256;
        #pragma unroll 4
        for (int e = 0; e < 16; ++e) {
            int p = fcol + e * 16;
            unsigned cv = X32[frow * XSTRD + p];
            float2 pwv = pwr[p];
            float2 cav = carrs[p];
            float fr = pwv.x * cav.x - pwv.y * cav.y;
            float fi = pwv.x * cav.y + pwv.y * cav.x;
            X32[frow * XSTRD + p] =
                packbf(bf2f(cv & 0xffffu) + fr, bf2f(cv >> 16) + fi);
        }
    }

    // ---------------- phase 5: GEMM2 (BM=32, BN=256, K=512) + D*u -----------------
    {
        const unsigned short* W2 = (const unsigned short*)(ws + OFF_W2T);
        char* Bsb2 = smem + BSB2_OFF;
        const char* Xb = (const char*)smem;
        floatx4 acc[2][2];
        #pragma unroll
        for (int i = 0; i < 2; ++i)
            #pragma unroll
            for (int j = 0; j < 2; ++j) acc[i][j] = (floatx4)0.0f;

        for (int k0 = 0; k0 < 512; k0 += 64) {
            if (k0) {
                __syncthreads();   // previous MFMA done; safe to overwrite Bsb2
                #pragma unroll
                for (int t = 0; t < 4; ++t) {
                    int idx = t * 8 + wave;        // 0..31
                    int pan = idx & 1, rowg = idx >> 1;
                    int row = rowg * 16 + r4;
                    async16(W2 + (size_t)row * 512 + k0 + pan * 32 + c4 * 8,
                            Bsb2 + pan * 16384 + row * 64 + c4 * 16);
                }
            }
            __syncthreads();       // staged panels visible (also fixup->MFMA at k0=0)
            #pragma unroll
            for (int ks = 0; ks < 2; ++ks) {
                short8 a[2], bfr[2];
                #pragma unroll
                for (int i = 0; i < 2; ++i)
                    a[i] = *(const short8*)(Xb + (i * 16 + rr) * (XSTRS * 2) +
                                            k0 * 2 + ks * 64 + q * 16);
                #pragma unroll
                for (int j = 0; j < 2; ++j)
                    bfr[j] = *(const short8*)(Bsb2 + ks * 16384 +
                                              (wave * 32 + j * 16 + rr) * 64 + q * 16);
                #pragma unroll
                for (int i = 0; i < 2; ++i)
                    #pragma unroll
                    for (int j = 0; j < 2; ++j)
                        acc[i][j] = __builtin_amdgcn_mfma_f32_16x16x32_bf16(a[i], bfr[j], acc[i][j], 0, 0, 0);
            }
        }

        #pragma unroll
        for (int i = 0; i < 2; ++i) {
            int mbase = m0 + i * 16 + q * 4;
            #pragma unroll
            for (int j = 0; j < 2; ++j) {
                int col = wave * 32 + j * 16 + rr;
                #pragma unroll
                for (int r0 = 0; r0 < 4; ++r0) {
                    int rw = mbase + r0;
                    size_t gi = (size_t)rw * 256 + col;
                    out[gi] = acc[i][j][r0] + D[col] * u[gi];
                }
            }
        }
    }
}

extern "C" void kernel_launch(void* const* d_in, const int* in_sizes, int n_in,
                              void* d_out, int out_size, void* d_ws, size_t ws_size,
                              hipStream_t stream) {
    const float* u  = (const float*)d_in[0];
    const float* Lr = (const float*)d_in[1];
    const float* Li = (const float*)d_in[2];
    const float* Bm = (const float*)d_in[3];
    const float* Cm = (const float*)d_in[4];
    const float* D  = (const float*)d_in[5];
    const float* ls = (const float*)d_in[6];
    float* out = (float*)d_out;
    char* ws = (char*)d_ws;

    // zero both tree-barrier instances (workspace is re-poisoned before every launch)
    hipMemsetAsync(ws + OFF_BAR, 0, 16384, stream);
    k_all<<<NCHUNK, 512, 69632, stream>>>(u, Lr, Li, ls, Bm, Cm, D, out, ws);
}